// Round 3
// baseline (159.708 us; speedup 1.0000x reference)
//
#include <hip/hip_runtime.h>

// MultiScaleRoIAlign (round 7): single fused kernel, no repack, no workspace.
// Rounds 0-2 showed the [B,C,H,W]->channels-last repack is structurally stuck
// at 2.2-3.3 TB/s and dominates (~49 of ~51 us); two-pass moves ~240 MB vs the
// ~126 MB the problem actually requires. This kernel gathers directly from
// NCHW fp32: block = (roi, c-quarter of 64). Per 8-channel tile it stages the
// roi's bilinear window (contiguous rows, coalesced) into LDS, then each
// thread samples one (channel, bin) output. Window size is bounded by the FPN
// level heuristic: w'*h' <= 784 at the assigned level -> nx*ny <= ~830 floats
// (cap 1024, with a direct-global fallback guard for safety).

#define ROI_OUT 7
#define NSAMP   14
#define C_TOT   256
#define N_PER_B 256
#define BINS    49
#define CT      8              // channels staged per tile
#define WCAP    1024           // max window floats per channel
#define WSTRIDE 1032           // +8 pad: c-slabs start on distinct banks
#define THREADS 512
#define CQ      64             // channels per block (quarter)

__global__ __launch_bounds__(THREADS)
void msroi_fused(const float* __restrict__ f0, const float* __restrict__ f1,
                 const float* __restrict__ f2, const float* __restrict__ f3,
                 const float* __restrict__ boxes, float* __restrict__ out)
{
    __shared__ float win[CT * WSTRIDE];   // 33 KB
    __shared__ int4  pY[NSAMP], pX[NSAMP];

    const int tid = threadIdx.x;
    const int roi = blockIdx.x;
    const int b   = roi >> 8;             // N_PER_B = 256

    // ---- box + level (block-uniform, identical to verified kernels) ----
    const float* bxp = boxes + (size_t)roi * 4;
    float bx1 = bxp[0], by1 = bxp[1], bx2 = bxp[2], by2 = bxp[3];
    float area = (bx2 - bx1) * (by2 - by1);
    float s    = sqrtf(area);
    float lvlf = floorf(4.0f + log2f(s * (1.0f / 224.0f)) + 1e-6f);
    lvlf = fminf(fmaxf(lvlf, 2.0f), 5.0f);
    int level = (int)lvlf - 2;

    const float* feat; int H, W; float scale;
    switch (level) {
        case 0:  feat = f0; H = 200; W = 200; scale = 0.25f;    break;
        case 1:  feat = f1; H = 100; W = 100; scale = 0.125f;   break;
        case 2:  feat = f2; H = 50;  W = 50;  scale = 0.0625f;  break;
        default: feat = f3; H = 25;  W = 25;  scale = 0.03125f; break;
    }
    const size_t HWsz = (size_t)H * (size_t)W;

    float x1 = bx1 * scale, y1 = by1 * scale;
    float roi_w = fmaxf(bx2 * scale - x1, 1.0f);
    float roi_h = fmaxf(by2 * scale - y1, 1.0f);
    float bin_w = roi_w * (1.0f / ROI_OUT);
    float bin_h = roi_h * (1.0f / ROI_OUT);

    // ---- sample-coordinate precompute (verified math) ----
    if (tid < 2 * NSAMP) {
        bool isy = tid >= NSAMP;
        int  j   = isy ? tid - NSAMP : tid;
        int  pb  = j >> 1, sub = j & 1;
        float start = isy ? y1 : x1;
        float bsz   = isy ? bin_h : bin_w;
        int   lim   = isy ? H : W;
        float ss = start + (float)pb * bsz + ((float)sub + 0.5f) * bsz * 0.5f;
        float v  = (ss >= -1.0f && ss <= (float)lim) ? 1.0f : 0.0f;
        float cc = fminf(fmaxf(ss, 0.0f), (float)lim - 1.0f);
        int   i0 = (int)floorf(cc);
        int   i1 = min(i0 + 1, lim - 1);
        float l  = cc - (float)i0;
        int4 pk; pk.x = i0; pk.y = i1;
        pk.z = __float_as_int(l); pk.w = __float_as_int(v);
        if (isy) pY[j] = pk; else pX[j] = pk;
    }
    __syncthreads();

    // ---- window bounds (redundant per thread, broadcast smem reads) ----
    int ylo = 1 << 30, yhi = 0, xlo = 1 << 30, xhi = 0;
    #pragma unroll
    for (int j = 0; j < NSAMP; ++j) {
        int4 py = pY[j]; int4 px = pX[j];
        ylo = min(ylo, py.x); yhi = max(yhi, py.y);
        xlo = min(xlo, px.x); xhi = max(xhi, px.y);
    }
    const int ny  = yhi - ylo + 1;
    const int nx  = xhi - xlo + 1;
    const int nyx = ny * nx;
    const bool staged = (nyx <= WCAP);    // provably true for this distribution

    const float* fbase = feat + (size_t)b * C_TOT * HWsz;
    float*       orow  = out + (size_t)roi * (C_TOT * BINS);
    const int    cq0   = blockIdx.y * CQ;

    for (int tile = 0; tile < CQ / CT; ++tile) {
        const int c0 = cq0 + tile * CT;

        __syncthreads();                  // previous tile's samplers done
        if (staged) {
            #pragma unroll
            for (int cl = 0; cl < CT; ++cl) {
                const float* pl = fbase + (size_t)(c0 + cl) * HWsz;
                float* wb = win + cl * WSTRIDE;
                for (unsigned j = tid; j < (unsigned)nyx; j += THREADS) {
                    unsigned yy = j / (unsigned)nx;
                    unsigned xx = j - yy * (unsigned)nx;
                    wb[j] = pl[(size_t)(ylo + (int)yy) * W + xlo + (int)xx];
                }
            }
        }
        __syncthreads();

        if (tid < CT * BINS) {
            int cl  = tid / BINS;
            int bin = tid - cl * BINS;
            int ph  = bin / ROI_OUT;
            int pw  = bin - ph * ROI_OUT;
            float acc = 0.0f;

            if (staged) {
                const float* wb = win + cl * WSTRIDE;
                #pragma unroll
                for (int sy = 0; sy < 2; ++sy) {
                    int4 py  = pY[2 * ph + sy];
                    float ly = __int_as_float(py.z);
                    float vy = __int_as_float(py.w);
                    float hy = 1.0f - ly;
                    int r0 = (py.x - ylo) * nx - xlo;
                    int r1 = (py.y - ylo) * nx - xlo;
                    #pragma unroll
                    for (int sx = 0; sx < 2; ++sx) {
                        int4 px  = pX[2 * pw + sx];
                        float lx = __int_as_float(px.z);
                        float vv = vy * __int_as_float(px.w);
                        float hx = 1.0f - lx;
                        float v00 = wb[r0 + px.x], v01 = wb[r0 + px.y];
                        float v10 = wb[r1 + px.x], v11 = wb[r1 + px.y];
                        acc += vv * (hy * (hx * v00 + lx * v01)
                                   + ly * (hx * v10 + lx * v11));
                    }
                }
            } else {
                const float* pl = fbase + (size_t)(c0 + cl) * HWsz;
                #pragma unroll
                for (int sy = 0; sy < 2; ++sy) {
                    int4 py  = pY[2 * ph + sy];
                    float ly = __int_as_float(py.z);
                    float vy = __int_as_float(py.w);
                    float hy = 1.0f - ly;
                    const float* r0 = pl + (size_t)py.x * W;
                    const float* r1 = pl + (size_t)py.y * W;
                    #pragma unroll
                    for (int sx = 0; sx < 2; ++sx) {
                        int4 px  = pX[2 * pw + sx];
                        float lx = __int_as_float(px.z);
                        float vv = vy * __int_as_float(px.w);
                        float hx = 1.0f - lx;
                        float v00 = r0[px.x], v01 = r0[px.y];
                        float v10 = r1[px.x], v11 = r1[px.y];
                        acc += vv * (hy * (hx * v00 + lx * v01)
                                   + ly * (hx * v10 + lx * v11));
                    }
                }
            }
            orow[(size_t)(c0 + cl) * BINS + bin] = acc * 0.25f;
        }
    }
}

extern "C" void kernel_launch(void* const* d_in, const int* in_sizes, int n_in,
                              void* d_out, int out_size, void* d_ws, size_t ws_size,
                              hipStream_t stream)
{
    const float* f0    = (const float*)d_in[0];
    const float* f1    = (const float*)d_in[1];
    const float* f2    = (const float*)d_in[2];
    const float* f3    = (const float*)d_in[3];
    const float* boxes = (const float*)d_in[4];
    float* out = (float*)d_out;

    // grid: x = roi (2*256), y = channel quarter; workspace unused.
    hipLaunchKernelGGL(msroi_fused, dim3(2 * N_PER_B, C_TOT / CQ), dim3(THREADS),
                       0, stream, f0, f1, f2, f3, boxes, out);
}